// Round 9
// baseline (312.308 us; speedup 1.0000x reference)
//
#include <hip/hip_runtime.h>
#include <math.h>

#define LSEQ 4096
#define NFFT 8192
#define NF   512     // kept frequency bins
#define NF2  1024    // 2*NF (cos/sin interleaved)
#define NH   768
#define NBH  6144    // 8*768
#define MROWS 6912   // NBH + NH (x rows + k rows share stage-A GEMM)
#define SPLIT_ROW 3584   // partial-1 row split (28*128: block-uniform at BM=128)

typedef __attribute__((ext_vector_type(8))) short short8;   // 8 bf16 (4 VGPRs)
typedef __attribute__((ext_vector_type(4))) float floatx4;  // MFMA accumulator

__device__ __forceinline__ unsigned short f2bf(float f) {
    unsigned int u = __float_as_uint(f);
    u += 0x7fff + ((u >> 16) & 1);       // round-to-nearest-even
    return (unsigned short)(u >> 16);
}

// direct HBM->LDS async copy, 16B/lane.  LDS dest = wave-uniform base + lane*16.
__device__ __forceinline__ void gld16(const unsigned short* g, const unsigned short* l) {
    __builtin_amdgcn_global_load_lds(
        (const __attribute__((address_space(1))) void*)g,
        (__attribute__((address_space(3))) void*)l, 16, 0, 0);
}

// -------- fused trig tables: T1[f2][n] and T2[n][f2], bf16 -----------------
__global__ void build_tables(unsigned short* __restrict__ T1,
                             unsigned short* __restrict__ T2) {
    __shared__ unsigned short tile[64][66];
    const int t = threadIdx.x;
    const int F0 = blockIdx.x * 64;
    const int N0 = blockIdx.y * 64;
#pragma unroll
    for (int i = 0; i < 16; ++i) {
        int r = (t >> 6) + i * 4;
        int c = t & 63;
        int f2 = F0 + r, n = N0 + c;
        int f = f2 >> 1;
        int p = (f * n) & (NFFT - 1);
        float th = (float)p * (float)(2.0 * M_PI / (double)NFFT);
        float s, cc;
        sincosf(th, &s, &cc);
        unsigned short v = f2bf((f2 & 1) ? s : cc);
        T1[(size_t)f2 * LSEQ + n] = v;
        tile[r][c] = v;
    }
    __syncthreads();
#pragma unroll
    for (int i = 0; i < 16; ++i) {
        int r = (t >> 6) + i * 4;
        int c = t & 63;
        T2[(size_t)(N0 + r) * NF2 + F0 + c] = tile[c][r];
    }
}

// -------- fp32 -> bf16 pack of [x ; k] into one [6912, 4096] matrix --------
__global__ void tobf16(const float* __restrict__ x, const float* __restrict__ kk,
                       unsigned short* __restrict__ o) {
    size_t e = ((size_t)blockIdx.x * 256 + threadIdx.x) * 4;
    const size_t XN = (size_t)NBH * LSEQ;
    const float* s = (e < XN) ? (x + e) : (kk + (e - XN));
    float4 v = *(const float4*)s;
    unsigned int lo = (unsigned int)f2bf(v.x) | ((unsigned int)f2bf(v.y) << 16);
    unsigned int hi = (unsigned int)f2bf(v.z) | ((unsigned int)f2bf(v.w) << 16);
    *(uint2*)(o + e) = make_uint2(lo, hi);
}

// ======== 128x256 single-buffer co-resident GEMM: C = A[M,K] x B^T[N,K] ====
// R8 budget: per-K-tile wall 5460 cyc = MFMA 2483 + LDS ~2050 + stage ~900
// with ZERO overlap -- 1 block/CU, barrier-locked waves can't overlap pipes
// (m114).  R9: restore co-residency.  256^2/8w can't co-reside (acc 64 AGPR
// + VGPR > 128/wave, LDS 128KB).  New shape:
//   BM=128, BN=256, BK=64, 8 waves (2x4 grid, 64x64/wave, acc 4x4 floatx4),
//   SINGLE 48KB LDS buffer, __launch_bounds__(512,4) => <=128 regs/wave
//   => 4 waves/SIMD => 2 blocks/CU.  The single-buffer stage stall of one
//   block hides under the co-resident block's MFMA phase.
// Grids: stage B 16x48=768 = 3x256 exactly (balanced, no tail);
//        stage A 4x54x2=432 (all resident, 176 CUs hold 2).
// Swizzle: same verified 3-bit XOR (R8: bank conflicts == 0).
__global__ __launch_bounds__(512, 4) void gemm1b(
    const unsigned short* __restrict__ A,   // [M,ldk] bf16
    const unsigned short* __restrict__ B,   // [N,ldk] bf16 (transposed operand)
    float* __restrict__ C,                  // z==0 target [M,N] fp32
    float* __restrict__ P1a,                // z==1 target, rows < SPLIT_ROW
    float* __restrict__ P1b,                // z==1 target, rows >= SPLIT_ROW
    int gx, int gy, int N, int ldk, int Ksub)
{
    constexpr int ASZ = 128 * 64;            // A tile, shorts (16 KB)
    constexpr int BSZ = 256 * 64;            // B tile, shorts (32 KB)
    __shared__ __align__(16) unsigned short S[ASZ + BSZ];   // 48 KB
    const int t = threadIdx.x;
    const int wid = t >> 6, l = t & 63;

    // chunked bijective XCD swizzle (nwg = 432 / 768, both %8==0)
    const int nwg = gridDim.x, bid = blockIdx.x;
    const int swz = (bid & 7) * (nwg >> 3) + (bid >> 3);
    const int bx = swz % gx;
    const int rem = swz / gx;
    const int by = rem % gy;
    const int bz = rem / gy;

    const int m0 = by * 128, n0 = bx * 256;
    const int wr = wid >> 2, wc = wid & 3;   // wave tile: rows wr*64, cols wc*64
    const int lq = l >> 4, lr = l & 15;
    const int kbase = bz * Ksub;
    const int NT = Ksub >> 6;                // K-tiles of 64

    // read side: element (row, k-slot g) at LDS slot g ^ (row&7); frag rows
    // = base + lr with base mult-16 -> row&7 = lr&7.  ks=1 slot = s0^4.
    const int s0 = lq ^ (lr & 7);
    const int aoff = (wr * 64 + lr) * 64 + s0 * 8;            // shorts
    const int boff = ASZ + (wc * 64 + lr) * 64 + s0 * 8;

    // stage side: linear gld16 dest; lane l covers row wid*8+(l>>3), LDS slot
    // l&7 -> global k-slot (l&7)^((l>>3)&7)  (row offsets are mult-64)
    const int gsl = (l & 7) ^ ((l >> 3) & 7);
    const unsigned short* pAs = A + (size_t)(m0 + wid * 8 + (l >> 3)) * ldk + kbase + gsl * 8;
    const unsigned short* pBs = B + (size_t)(n0 + wid * 8 + (l >> 3)) * ldk + kbase + gsl * 8;

    floatx4 acc[4][4];
#pragma unroll
    for (int i = 0; i < 4; ++i)
#pragma unroll
        for (int j = 0; j < 4; ++j)
            acc[i][j] = (floatx4){0.f, 0.f, 0.f, 0.f};

    for (int kt = 0; kt < NT; ++kt) {
        // stage tile kt: A 2 calls (128 rows), B 4 calls (256 rows)
#pragma unroll
        for (int h = 0; h < 2; ++h)
            gld16(pAs + (size_t)(64 * h) * ldk + kt * 64, S + (64 * h + wid * 8) * 64);
#pragma unroll
        for (int h = 0; h < 4; ++h)
            gld16(pBs + (size_t)(64 * h) * ldk + kt * 64, S + ASZ + (64 * h + wid * 8) * 64);
        asm volatile("s_waitcnt vmcnt(0)" ::: "memory");
        __builtin_amdgcn_s_barrier();            // publish tile kt
        __builtin_amdgcn_sched_barrier(0);

        short8 bq[4][2];
#pragma unroll
        for (int j = 0; j < 4; ++j)
#pragma unroll
            for (int ks = 0; ks < 2; ++ks)
                bq[j][ks] = *(const short8*)(S + ((boff ^ (ks * 32)) + 1024 * j));
#pragma unroll
        for (int i = 0; i < 4; ++i) {
            short8 aq[2];
#pragma unroll
            for (int ks = 0; ks < 2; ++ks)
                aq[ks] = *(const short8*)(S + ((aoff ^ (ks * 32)) + 1024 * i));
            __builtin_amdgcn_s_setprio(1);
#pragma unroll
            for (int j = 0; j < 4; ++j)
#pragma unroll
                for (int ks = 0; ks < 2; ++ks)
                    acc[i][j] = __builtin_amdgcn_mfma_f32_16x16x32_bf16(
                        aq[ks], bq[j][ks], acc[i][j], 0, 0, 0);
            __builtin_amdgcn_s_setprio(0);
        }
        __builtin_amdgcn_s_barrier();   // retire all reads before next overwrite
    }

    // epilogue target: z=0 -> C; z=1 -> partial (block-uniform row split)
    float* Cb;
    if (bz == 0) Cb = C;
    else Cb = (m0 < SPLIT_ROW) ? P1a : (P1b - (size_t)SPLIT_ROW * N);
    // C/D layout: col = lane&15, row = (lane>>4)*4 + reg  [verified m89/m91]
#pragma unroll
    for (int i = 0; i < 4; ++i)
#pragma unroll
        for (int j = 0; j < 4; ++j)
#pragma unroll
            for (int r = 0; r < 4; ++r) {
                int row = m0 + wr * 64 + 16 * i + lq * 4 + r;
                int col = n0 + wc * 64 + 16 * j + lr;
                Cb[(size_t)row * N + col] = acc[i][j][r];
            }
}

// -------- combine: sum K-split partials + complex multiply + scaling -------
__global__ void combine(const float* __restrict__ C1,
                        const float* __restrict__ P1a,
                        const float* __restrict__ P1b,
                        unsigned short* __restrict__ AB) {
    int idx = blockIdx.x * blockDim.x + threadIdx.x;   // bh*512 + f
    int bh = idx >> 9;
    int f = idx & (NF - 1);
    int h = bh % NH;
    const float* xc = C1 + (size_t)bh * NF2 + 2 * f;
    const float* xp = (bh < SPLIT_ROW)
        ? (P1a + (size_t)bh * NF2 + 2 * f)
        : (P1b + (size_t)(bh - SPLIT_ROW) * NF2 + 2 * f);
    const int kr = NBH + h;    // always >= SPLIT_ROW
    const float* kc = C1 + (size_t)kr * NF2 + 2 * f;
    const float* kp = P1b + (size_t)(kr - SPLIT_ROW) * NF2 + 2 * f;
    float Xre = xc[0] + xp[0], Xim = -(xc[1] + xp[1]);
    float Kre = kc[0] + kp[0], Kim = -(kc[1] + kp[1]);
    float s = (f == 0 ? 1.0f : 2.0f) * (1.0f / (float)NFFT);
    float Av = s * (Xre * Kre - Xim * Kim);
    float Bv = -(s * (Xre * Kim + Xim * Kre));
    unsigned int packed = (unsigned int)f2bf(Av) | ((unsigned int)f2bf(Bv) << 16);
    *(unsigned int*)(AB + (size_t)bh * NF2 + 2 * f) = packed;
}

extern "C" void kernel_launch(void* const* d_in, const int* in_sizes, int n_in,
                              void* d_out, int out_size, void* d_ws, size_t ws_size,
                              hipStream_t stream) {
    const float* x = (const float*)d_in[0];   // [8,768,4096]
    const float* k = (const float*)d_in[1];   // [768,4096]
    float* y = (float*)d_out;

    // ws layout (44.0 MB of 45.1 MB proven):
    unsigned short* T1 = (unsigned short*)d_ws;                 // [1024,4096] bf16,  8.39 MB
    unsigned short* T2 = T1 + (size_t)NF2 * LSEQ;               // [4096,1024] bf16,  8.39 MB
    unsigned short* AB = T2 + (size_t)LSEQ * NF2;               // [6144,1024] bf16, 12.58 MB
    float* P1a = (float*)(AB + (size_t)NBH * NF2);              // [3584,1024] f32,  14.68 MB

    // d_out as scratch (98.6 MB of 100.66) until stage B overwrites:
    unsigned short* Abm = (unsigned short*)d_out;               // [6912,4096] bf16, 56.62 MB
    float* C1 = (float*)((char*)d_out + (size_t)MROWS * LSEQ * 2); // [6912,1024] f32, 28.31 MB
    float* P1b = C1 + (size_t)MROWS * NF2;                      // [3328,1024] f32,  13.63 MB

    const int blk = 256;
    hipLaunchKernelGGL(build_tables, dim3(NF2 / 64, LSEQ / 64), dim3(blk), 0, stream, T1, T2);
    hipLaunchKernelGGL(tobf16, dim3((MROWS * LSEQ / 4) / blk), dim3(blk), 0, stream, x, k, Abm);
    // Stage A: [6912,4096] x [4096,1024], 128x256 tiles, split-K x2: 4*54*2=432 WGs
    hipLaunchKernelGGL(gemm1b, dim3(4 * 54 * 2), dim3(512), 0, stream,
                       Abm, T1, C1, P1a, P1b, 4, 54, NF2, LSEQ, LSEQ / 2);
    hipLaunchKernelGGL(combine, dim3((NBH * NF) / blk), dim3(blk), 0, stream, C1, P1a, P1b, AB);
    // Stage B: [6144,1024] x [1024,4096] -> y: 16*48=768 WGs (3 per CU exactly)
    hipLaunchKernelGGL(gemm1b, dim3(16 * 48), dim3(512), 0, stream,
                       AB, T2, y, (float*)nullptr, (float*)nullptr, 16, 48, LSEQ, NF2, NF2);
}